// Round 18
// baseline (85.344 us; speedup 1.0000x reference)
//
#include <hip/hip_runtime.h>
#include <hip/hip_bf16.h>
#include <math.h>

typedef __attribute__((ext_vector_type(4))) float f32x4;
typedef __attribute__((ext_vector_type(8))) short bf16x8;
typedef unsigned int u32;
typedef unsigned short u16;

__device__ __forceinline__ short f2bf(float f) {
    u32 u = __builtin_bit_cast(u32, f);
    u = (u + 0x7FFFu + ((u >> 16) & 1u)) >> 16;
    return (short)u;
}

__device__ __forceinline__ float exp2n(float x) {   // native v_exp_f32
    return __builtin_amdgcn_exp2f(x);
}

__device__ __forceinline__ void gload_lds16(const void* g, void* l) {
    __builtin_amdgcn_global_load_lds(
        (__attribute__((address_space(1))) u32*)g,
        (__attribute__((address_space(3))) u32*)l,
        16, 0, 0);
}

// ---------- transpose + fp32->bf16 convert: src[R][C] -> dst[C][R] ----------
// (weights only; x is fused into gemm_qkv)
__global__ void transpose_cvt(const float* __restrict__ src, short* __restrict__ dst,
                              int R, int C) {
    __shared__ float tile[32][33];
    const int c0 = blockIdx.x * 32, r0 = blockIdx.y * 32;
    const size_t base = (size_t)blockIdx.z * R * C;
    const int tx = threadIdx.x, ty = threadIdx.y;
#pragma unroll
    for (int i = 0; i < 32; i += 8)
        tile[ty + i][tx] = src[base + (size_t)(r0 + ty + i) * C + c0 + tx];
    __syncthreads();
    const int lflat = ty * 32 + tx;
    const int cc = lflat >> 4;        // 0..15
    const int rp = lflat & 15;        // 0..15 (R-pair index)
#pragma unroll
    for (int i = 0; i < 2; ++i) {
        const int c = cc + i * 16;
        const u32 lo = (u16)f2bf(tile[rp * 2][c]);
        const u32 hi = (u16)f2bf(tile[rp * 2 + 1][c]);
        *(u32*)&dst[base + (size_t)(c0 + c) * R + r0 + rp * 2] = lo | (hi << 16);
    }
}

// ---------- GEMM1 (x-fused, 128x128 tile, 8 waves): qkv = x^T @ w_qkv + b ----------
// Xg = x fp32 [8][512 c][1024 n]; Bt = wqkvT bf16 [1536][512].
// 512 threads, 8 waves (2M x 4N), grid 768 = 3 blocks/CU -> 24 waves/CU (was 12).
// Per-block staging totals identical to the r14 128x128 version (one B panel +
// one A tile per K-step); per-thread: 1 gload_lds16 + 8 dword + 1 ds_write_b128.
// A-write banks: toks 0..7 x swizzled chunks cover all 32 banks once (no aliasing).
// Q pre-scaled by 0.125*log2(e). V written transposed via wave-private LDS.
__global__ __launch_bounds__(512, 4) void gemm_qkv(
    const float* __restrict__ Xg, const short* __restrict__ Bt,
    const float* __restrict__ bias,
    short* __restrict__ Qo, short* __restrict__ Ko, short* __restrict__ Vto) {
    __shared__ short As[2][128 * 32];   // 16 KB
    __shared__ short Bs[2][128 * 32];   // 16 KB
    const int t = threadIdx.x, w = t >> 6, l = t & 63;
    // bijective XCD swizzle: 768 blocks = 8 XCD x 96
    const int bid = blockIdx.x;
    const int sbid = (bid & 7) * 96 + (bid >> 3);
    const int n0 = (sbid % 12) * 128, m0 = (sbid / 12) * 128;
    const int srow = t >> 2;                        // B staging row 0..127
    const int sgc = (t & 3) ^ ((t >> 3) & 3);       // pre-swizzled source chunk
    // A reg-staging: one token per thread (tok 0..127), 8 c-values
    const int tok = t & 127, ch = t >> 7;           // ch 0..3
    const int xb = m0 >> 10;
    const int xn = (m0 & 1023) + tok;
    const int akey = (tok >> 1) & 3;
    f32x4 acc[4][2] = {};
    const int wmr = (w >> 2) * 64, wnr = (w & 3) * 32;
    const int lg = l >> 4, li = l & 15;
    const int rc = (lg ^ ((li >> 1) & 3)) * 8;      // swizzled read chunk (shorts)

    auto stageB = [&](int buf, int k0) {
        gload_lds16(Bt + (size_t)(n0 + srow) * 512 + k0 + sgc * 8, Bs[buf] + t * 8);
    };
    auto loadA = [&](int k0, float* a) {
        const float* p = Xg + ((size_t)xb * 512 + k0 + ch * 8) * 1024 + xn;
#pragma unroll
        for (int i = 0; i < 8; ++i) a[i] = p[(size_t)i * 1024];
    };
    auto writeA = [&](int buf, const float* a) {
        bf16x8 v;
#pragma unroll
        for (int i = 0; i < 8; ++i) v[i] = f2bf(a[i]);
        *(bf16x8*)&As[buf][tok * 32 + (ch ^ akey) * 8] = v;
    };

    {   // prologue: tile 0
        float a[8];
        stageB(0, 0);
        loadA(0, a);
        writeA(0, a);
    }
    __syncthreads();
    for (int kt = 0; kt < 16; ++kt) {
        const int cur = kt & 1;
        float a[8];
        if (kt + 1 < 16) {
            stageB(cur ^ 1, (kt + 1) * 32);
            loadA((kt + 1) * 32, a);        // HBM/L2 latency hides under MFMAs
        }
        bf16x8 af[4], bf_[2];
#pragma unroll
        for (int mt = 0; mt < 4; ++mt)
            af[mt] = *(const bf16x8*)&As[cur][(wmr + mt * 16 + li) * 32 + rc];
#pragma unroll
        for (int nt = 0; nt < 2; ++nt)
            bf_[nt] = *(const bf16x8*)&Bs[cur][(wnr + nt * 16 + li) * 32 + rc];
        __builtin_amdgcn_s_setprio(1);
#pragma unroll
        for (int mt = 0; mt < 4; ++mt)
#pragma unroll
            for (int nt = 0; nt < 2; ++nt)
                acc[mt][nt] = __builtin_amdgcn_mfma_f32_16x16x32_bf16(af[mt], bf_[nt], acc[mt][nt], 0, 0, 0);
        __builtin_amdgcn_s_setprio(0);
        if (kt + 1 < 16) writeA(cur ^ 1, a);   // write-late (T14)
        __syncthreads();
    }
    // epilogue: each wave owns a 32-col window; tsel block-uniform (n0 128-aligned,
    // wnr < 128, 512-boundaries are multiples of 128)
    const int colbase = n0 + wnr;
    const int tsel = colbase >> 9;
    const int h = (colbase & 511) >> 6;
    const int dcol = colbase & 63;          // 0 or 32 within head h
    if (tsel < 2) {
        short* __restrict__ dst = (tsel == 0) ? Qo : Ko;
        const float scale = (tsel == 0) ? 0.180336878f : 1.0f;   // 0.125*log2(e)
#pragma unroll
        for (int nt = 0; nt < 2; ++nt) {
            const int d = nt * 16 + li;
            const float bv = bias[colbase + d];
#pragma unroll
            for (int mt = 0; mt < 4; ++mt) {
                const int rowb = m0 + wmr + mt * 16 + lg * 4;
#pragma unroll
                for (int r = 0; r < 4; ++r) {
                    const int row = rowb + r;
                    const int bb = row >> 10, np = row & 1023;
                    const float v = (acc[mt][nt][r] + bv) * scale;
                    dst[((size_t)(bb * 8 + h) * 1024 + np) * 64 + dcol + d] = f2bf(v);
                }
            }
        }
    } else {
        // V: wave-private LDS transpose (As/Bs free after final barrier). 4 KB/wave.
        short* vq = (w < 4) ? ((short*)As + w * 2048) : ((short*)Bs + (w - 4) * 2048);
#pragma unroll
        for (int nt = 0; nt < 2; ++nt) {
            const int dl = nt * 16 + li;     // local d 0..31
            const float bv = bias[colbase + nt * 16 + li];
#pragma unroll
            for (int mt = 0; mt < 4; ++mt)
#pragma unroll
                for (int r = 0; r < 4; ++r) {
                    const int tk = mt * 16 + lg * 4 + r;   // local token 0..63
                    vq[dl * 64 + (((tk >> 3) ^ (dl & 7)) * 8) + (tk & 7)] =
                        f2bf(acc[mt][nt][r] + bv);
                }
        }
        const int bh = (m0 >> 10) * 8 + h;
        const int np0 = (m0 & 1023) + wmr;
#pragma unroll
        for (int pass = 0; pass < 4; ++pass) {
            const int dd = (l >> 3) + pass * 8;   // 0..31
            const int cc = l & 7;
            const bf16x8 vv = *(const bf16x8*)&vq[dd * 64 + ((cc ^ (dd & 7)) * 8)];
            *(bf16x8*)&Vto[((size_t)bh * 64 + dcol + dd) * 1024 + np0 + cc * 8] = vv;
        }
    }
}

// ---------- attention: flash over 64-key tiles, K single-buffered ----------
// LDS 32 KB; launch_bounds 4 (r15's (256,5) choked the allocator to 48 VGPR +
// scratch spill). HW reaches 5 blocks/CU via the LDS limit with full VGPR budget.
__global__ __launch_bounds__(256, 4) void attn_kernel(
    const short* __restrict__ Qg, const short* __restrict__ Kg,
    const short* __restrict__ Vtg, short* __restrict__ Og) {
    __shared__ short Ks[64 * 64];
    __shared__ short Vts[2][64 * 64];
    __shared__ short Ps[4][16 * 64];
    const int t = threadIdx.x, w = t >> 6, l = t & 63, lg = l >> 4, li = l & 15;
    // bijective XCD swizzle: 1024 blocks = 8 XCD x 128 -> 8 bh per XCD
    const int bid = blockIdx.x;
    const int sbid = (bid & 7) * 128 + (bid >> 3);
    const int n0 = (sbid & 15) * 64;
    const int bh = sbid >> 4;
    const int b = bh >> 3, h = bh & 7;

    const int qa = n0 + w * 16 + li;
    const size_t qbase = ((size_t)bh * 1024 + qa) * 64;
    const bf16x8 aq0 = *(const bf16x8*)&Qg[qbase + lg * 8];
    const bf16x8 aq1 = *(const bf16x8*)&Qg[qbase + 32 + lg * 8];

    bf16x8 onesb;
#pragma unroll
    for (int i = 0; i < 8; ++i) onesb[i] = (short)0x3F80;   // bf16 1.0

    f32x4 oacc[4] = {};
    f32x4 oner = {};
    float mrow[4] = {-1e30f, -1e30f, -1e30f, -1e30f};

    const int srow = t >> 3;
    const int sgc = (t & 7) ^ ((t >> 3) & 7);
    const int kc0 = (lg ^ (li & 7)) * 8;
    const int kc1 = kc0 ^ 32;

    auto stageK = [&](int ktile) {
        const int kt = ktile * 64;
        gload_lds16(Kg + ((size_t)bh * 1024 + kt + srow) * 64 + sgc * 8, Ks + t * 8);
        gload_lds16(Kg + ((size_t)bh * 1024 + kt + srow + 32) * 64 + sgc * 8, Ks + (t + 256) * 8);
    };
    auto stageV = [&](int buf, int ktile) {
        const int kt = ktile * 64;
        short* vb = Vts[buf];
        gload_lds16(Vtg + ((size_t)bh * 64 + srow) * 1024 + kt + sgc * 8, vb + t * 8);
        gload_lds16(Vtg + ((size_t)bh * 64 + srow + 32) * 1024 + kt + sgc * 8, vb + (t + 256) * 8);
    };

    stageK(0);
    stageV(0, 0);
    __syncthreads();
    for (int kt = 0; kt < 16; ++kt) {
        const int cur = kt & 1;
        const short* vb = Vts[cur];

        // S = Q K^T from the single K buffer (holds tile kt)
        f32x4 s[4];
        __builtin_amdgcn_s_setprio(1);
#pragma unroll
        for (int nt = 0; nt < 4; ++nt) {
            const int krow = (nt * 16 + li) * 64;
            const bf16x8 bk0 = *(const bf16x8*)&Ks[krow + kc0];
            const bf16x8 bk1 = *(const bf16x8*)&Ks[krow + kc1];
            f32x4 z = {};
            z = __builtin_amdgcn_mfma_f32_16x16x32_bf16(aq0, bk0, z, 0, 0, 0);
            z = __builtin_amdgcn_mfma_f32_16x16x32_bf16(aq1, bk1, z, 0, 0, 0);
            s[nt] = z;
        }
        __builtin_amdgcn_s_setprio(0);
        // all waves done reading K(kt); vmcnt already 0 here -> cheap barrier
        __syncthreads();
        if (kt + 1 < 16) {
            stageK(kt + 1);              // covered by softmax+P+PV below
            stageV(cur ^ 1, kt + 1);
        }

        // online softmax (base-2), defer-max
        float lm[4];
#pragma unroll
        for (int r = 0; r < 4; ++r)
            lm[r] = fmaxf(fmaxf(s[0][r], s[1][r]), fmaxf(s[2][r], s[3][r]));
        const float excess = fmaxf(fmaxf(lm[0] - mrow[0], lm[1] - mrow[1]),
                                   fmaxf(lm[2] - mrow[2], lm[3] - mrow[3]));
        if (__all(excess <= 8.0f)) {
#pragma unroll
            for (int nt = 0; nt < 4; ++nt)
#pragma unroll
                for (int r = 0; r < 4; ++r)
                    s[nt][r] = exp2n(s[nt][r] - mrow[r]);
        } else {
            float mnew[4], sc[4];
#pragma unroll
            for (int r = 0; r < 4; ++r) {
                float v = lm[r];
#pragma unroll
                for (int mm = 8; mm >= 1; mm >>= 1) v = fmaxf(v, __shfl_xor(v, mm));
                mnew[r] = fmaxf(mrow[r], v);
                sc[r] = exp2n(mrow[r] - mnew[r]);
                mrow[r] = mnew[r];
            }
#pragma unroll
            for (int nt = 0; nt < 4; ++nt)
#pragma unroll
                for (int r = 0; r < 4; ++r)
                    s[nt][r] = exp2n(s[nt][r] - mnew[r]);
#pragma unroll
            for (int dt = 0; dt < 4; ++dt)
#pragma unroll
                for (int r = 0; r < 4; ++r) oacc[dt][r] *= sc[r];
#pragma unroll
            for (int r = 0; r < 4; ++r) oner[r] *= sc[r];
        }

        // P -> LDS (swizzled), packed bf16 convert (wave-private)
#pragma unroll
        for (int nt = 0; nt < 4; ++nt)
#pragma unroll
            for (int rp = 0; rp < 2; ++rp) {
                u32 pk;
                asm("v_cvt_pk_bf16_f32 %0, %1, %2"
                    : "=v"(pk) : "v"(s[nt][rp * 2]), "v"(s[nt][rp * 2 + 1]));
                const int prow0 = lg * 4 + rp * 2;
                const int pcbase = nt * 2 + (li >> 3);
                Ps[w][prow0 * 64 + (pcbase ^ (prow0 & 7)) * 8 + (li & 7)] = (short)pk;
                Ps[w][(prow0 + 1) * 64 + (pcbase ^ ((prow0 + 1) & 7)) * 8 + (li & 7)] =
                    (short)(pk >> 16);
            }
        const bf16x8 pa0 = *(const bf16x8*)&Ps[w][li * 64 + kc0];
        const bf16x8 pa1 = *(const bf16x8*)&Ps[w][li * 64 + kc1];
        __builtin_amdgcn_s_setprio(1);
        oner = __builtin_amdgcn_mfma_f32_16x16x32_bf16(pa0, onesb, oner, 0, 0, 0);
        oner = __builtin_amdgcn_mfma_f32_16x16x32_bf16(pa1, onesb, oner, 0, 0, 0);
#pragma unroll
        for (int dt = 0; dt < 4; ++dt) {
            const int vrow = (dt * 16 + li) * 64;
            const bf16x8 bv0 = *(const bf16x8*)&vb[vrow + kc0];
            const bf16x8 bv1 = *(const bf16x8*)&vb[vrow + kc1];
            oacc[dt] = __builtin_amdgcn_mfma_f32_16x16x32_bf16(pa0, bv0, oacc[dt], 0, 0, 0);
            oacc[dt] = __builtin_amdgcn_mfma_f32_16x16x32_bf16(pa1, bv1, oacc[dt], 0, 0, 0);
        }
        __builtin_amdgcn_s_setprio(0);
        // drains this iter's K/V staging; next iter reads them
        __syncthreads();
    }
#pragma unroll
    for (int r = 0; r < 4; ++r) {
        const float inv = 1.f / oner[r];
        const int qq = n0 + w * 16 + lg * 4 + r;
#pragma unroll
        for (int dt = 0; dt < 4; ++dt)
            Og[(size_t)(b * 1024 + qq) * 512 + h * 64 + dt * 16 + li] = f2bf(oacc[dt][r] * inv);
    }
}

// ---------- GEMM2 (8-wave): outT[c][n] = wprojT[c][:] . O[n][:] + b_proj[c] ----------
__global__ __launch_bounds__(512, 2) void gemm_proj(
    const short* __restrict__ At, const short* __restrict__ Bsrc,
    const float* __restrict__ bias, float* __restrict__ out) {
    __shared__ short As[2][128 * 32];
    __shared__ short Bs[2][128 * 32];
    const int t = threadIdx.x, w = t >> 6, l = t & 63;
    const int n0 = blockIdx.x * 128, m0 = blockIdx.y * 128, bz = blockIdx.z;
    const int srow = t >> 2;                        // 0..127
    const int sgc = (t & 3) ^ ((t >> 3) & 3);
    f32x4 acc[4][2] = {};
    const int wmr = (w >> 2) * 64, wnr = (w & 3) * 32;
    const int lg = l >> 4, li = l & 15;
    const int rc = (lg ^ ((li >> 1) & 3)) * 8;

    auto stage = [&](int buf, int k0) {
        gload_lds16(At + (size_t)(m0 + srow) * 512 + k0 + sgc * 8, As[buf] + t * 8);
        gload_lds16(Bsrc + ((size_t)bz * 1024 + n0 + srow) * 512 + k0 + sgc * 8, Bs[buf] + t * 8);
    };

    stage(0, 0);
    __syncthreads();
    for (int kt = 0; kt < 16; ++kt) {
        const int cur = kt & 1;
        if (kt + 1 < 16) stage(cur ^ 1, (kt + 1) * 32);
        bf16x8 af[4], bf_[2];
#pragma unroll
        for (int mt = 0; mt < 4; ++mt)
            af[mt] = *(const bf16x8*)&As[cur][(wmr + mt * 16 + li) * 32 + rc];
#pragma unroll
        for (int nt = 0; nt < 2; ++nt)
            bf_[nt] = *(const bf16x8*)&Bs[cur][(wnr + nt * 16 + li) * 32 + rc];
        __builtin_amdgcn_s_setprio(1);
#pragma unroll
        for (int mt = 0; mt < 4; ++mt)
#pragma unroll
            for (int nt = 0; nt < 2; ++nt)
                acc[mt][nt] = __builtin_amdgcn_mfma_f32_16x16x32_bf16(af[mt], bf_[nt], acc[mt][nt], 0, 0, 0);
        __builtin_amdgcn_s_setprio(0);
        __syncthreads();
    }
#pragma unroll
    for (int mt = 0; mt < 4; ++mt)
#pragma unroll
        for (int r = 0; r < 4; ++r) {
            const int c = m0 + wmr + mt * 16 + lg * 4 + r;
            const float bv = bias[c];
#pragma unroll
            for (int nt = 0; nt < 2; ++nt) {
                const int col = n0 + wnr + nt * 16 + li;
                out[(size_t)(bz * 512 + c) * 1024 + col] = acc[mt][nt][r] + bv;
            }
        }
}

extern "C" void kernel_launch(void* const* d_in, const int* in_sizes, int n_in,
                              void* d_out, int out_size, void* d_ws, size_t ws_size,
                              hipStream_t stream) {
    const float* x      = (const float*)d_in[0];   // (8,512,1024)
    const float* w_qkv  = (const float*)d_in[1];   // (512,1536)
    const float* b_qkv  = (const float*)d_in[2];   // (1536)
    const float* w_proj = (const float*)d_in[3];   // (512,512)
    const float* b_proj = (const float*)d_in[4];   // (512)
    float* out = (float*)d_out;                    // (8,512,1024)

    char* ws = (char*)d_ws;
    size_t off = 0;
    auto carve = [&](size_t bytes) {
        void* p = ws + off;
        off = (off + bytes + 255) & ~(size_t)255;
        return p;
    };
    short* wqkvT  = (short*)carve((size_t)1536 * 512 * 2);
    short* wprojT = (short*)carve((size_t)512 * 512 * 2);
    short* Q      = (short*)carve((size_t)8 * 8 * 1024 * 64 * 2);
    short* K      = (short*)carve((size_t)8 * 8 * 1024 * 64 * 2);
    short* Vt     = (short*)carve((size_t)8 * 8 * 64 * 1024 * 2);
    short* O      = (short*)carve((size_t)8 * 1024 * 512 * 2);

    dim3 tb(32, 8);
    transpose_cvt<<<dim3(1536 / 32, 512 / 32, 1), tb, 0, stream>>>(w_qkv, wqkvT, 512, 1536);
    transpose_cvt<<<dim3(512 / 32, 512 / 32, 1), tb, 0, stream>>>(w_proj, wprojT, 512, 512);
    gemm_qkv<<<dim3(768), 512, 0, stream>>>(x, wqkvT, b_qkv, Q, K, Vt);
    attn_kernel<<<dim3(1024), 256, 0, stream>>>(Q, K, Vt, O);
    gemm_proj<<<dim3(8, 4, 8), 512, 0, stream>>>(wprojT, O, b_proj, out);
}

// Round 19
// 79.584 us; speedup vs baseline: 1.0724x; 1.0724x over previous
//
#include <hip/hip_runtime.h>
#include <hip/hip_bf16.h>
#include <math.h>

typedef __attribute__((ext_vector_type(4))) float f32x4;
typedef __attribute__((ext_vector_type(8))) short bf16x8;
typedef unsigned int u32;
typedef unsigned short u16;

__device__ __forceinline__ short f2bf(float f) {
    u32 u = __builtin_bit_cast(u32, f);
    u = (u + 0x7FFFu + ((u >> 16) & 1u)) >> 16;
    return (short)u;
}

__device__ __forceinline__ float exp2n(float x) {   // native v_exp_f32
    return __builtin_amdgcn_exp2f(x);
}

__device__ __forceinline__ void gload_lds16(const void* g, void* l) {
    __builtin_amdgcn_global_load_lds(
        (__attribute__((address_space(1))) u32*)g,
        (__attribute__((address_space(3))) u32*)l,
        16, 0, 0);
}

// ---------- transpose + fp32->bf16 convert: src[R][C] -> dst[C][R] ----------
// (weights only; x is fused into gemm_qkv)
__global__ void transpose_cvt(const float* __restrict__ src, short* __restrict__ dst,
                              int R, int C) {
    __shared__ float tile[32][33];
    const int c0 = blockIdx.x * 32, r0 = blockIdx.y * 32;
    const size_t base = (size_t)blockIdx.z * R * C;
    const int tx = threadIdx.x, ty = threadIdx.y;
#pragma unroll
    for (int i = 0; i < 32; i += 8)
        tile[ty + i][tx] = src[base + (size_t)(r0 + ty + i) * C + c0 + tx];
    __syncthreads();
    const int lflat = ty * 32 + tx;
    const int cc = lflat >> 4;        // 0..15
    const int rp = lflat & 15;        // 0..15 (R-pair index)
#pragma unroll
    for (int i = 0; i < 2; ++i) {
        const int c = cc + i * 16;
        const u32 lo = (u16)f2bf(tile[rp * 2][c]);
        const u32 hi = (u16)f2bf(tile[rp * 2 + 1][c]);
        *(u32*)&dst[base + (size_t)(c0 + c) * R + r0 + rp * 2] = lo | (hi << 16);
    }
}

// ---------- GEMM1 (x-transpose FUSED, conflict-free): qkv = x^T @ w_qkv + b ----------
// Xg = x fp32 [8][512 c][1024 n]; Bt = wqkvT bf16 [1536][512].
// A-staging: ONE token per thread (tok=t&127, ch=t>>7), 16 coalesced dword loads,
// 2 x ds_write_b128 at chunk position (ch*2+q)^((tok>>1)&3) -> zero bank aliasing.
// Q pre-scaled by 0.125*log2(e). V written transposed via wave-private LDS.
__global__ __launch_bounds__(256, 3) void gemm_qkv(
    const float* __restrict__ Xg, const short* __restrict__ Bt,
    const float* __restrict__ bias,
    short* __restrict__ Qo, short* __restrict__ Ko, short* __restrict__ Vto) {
    __shared__ short As[2][128 * 32];
    __shared__ short Bs[2][128 * 32];
    const int t = threadIdx.x, w = t >> 6, l = t & 63;
    // bijective XCD swizzle: 768 blocks = 8 XCD x 96
    const int bid = blockIdx.x;
    const int sbid = (bid & 7) * 96 + (bid >> 3);
    const int n0 = (sbid % 12) * 128, m0 = (sbid / 12) * 128;
    const int srow = t >> 2;                        // B staging row 0..63 (x2)
    const int sgc = (t & 3) ^ ((t >> 3) & 3);       // pre-swizzled source chunk
    // A reg-staging: one token per thread
    const int tok = t & 127, ch = t >> 7;
    const int xb = m0 >> 10;
    const int xn = (m0 & 1023) + tok;
    const int akey = (tok >> 1) & 3;
    f32x4 acc[4][4] = {};
    const int wmr = (w >> 1) * 64, wnr = (w & 1) * 64;
    const int lg = l >> 4, li = l & 15;
    const int rc = (lg ^ ((li >> 1) & 3)) * 8;      // swizzled read chunk (shorts)

    auto stageB = [&](int buf, int k0) {
        gload_lds16(Bt + (size_t)(n0 + srow) * 512 + k0 + sgc * 8, Bs[buf] + t * 8);
        gload_lds16(Bt + (size_t)(n0 + srow + 64) * 512 + k0 + sgc * 8, Bs[buf] + (t + 256) * 8);
    };
    auto loadA = [&](int k0, float* a) {
        const float* p = Xg + ((size_t)xb * 512 + k0 + ch * 16) * 1024 + xn;
#pragma unroll
        for (int i = 0; i < 16; ++i) a[i] = p[(size_t)i * 1024];
    };
    auto writeA = [&](int buf, const float* a) {
#pragma unroll
        for (int q = 0; q < 2; ++q) {
            bf16x8 v;
#pragma unroll
            for (int i = 0; i < 8; ++i) v[i] = f2bf(a[q * 8 + i]);
            *(bf16x8*)&As[buf][tok * 32 + ((ch * 2 + q) ^ akey) * 8] = v;
        }
    };

    {   // prologue: tile 0
        float a[16];
        stageB(0, 0);
        loadA(0, a);
        writeA(0, a);
    }
    __syncthreads();
    for (int kt = 0; kt < 16; ++kt) {
        const int cur = kt & 1;
        float a[16];
        if (kt + 1 < 16) {
            stageB(cur ^ 1, (kt + 1) * 32);
            loadA((kt + 1) * 32, a);        // HBM latency hides under MFMAs
        }
        bf16x8 af[4], bf_[4];
#pragma unroll
        for (int mt = 0; mt < 4; ++mt)
            af[mt] = *(const bf16x8*)&As[cur][(wmr + mt * 16 + li) * 32 + rc];
#pragma unroll
        for (int nt = 0; nt < 4; ++nt)
            bf_[nt] = *(const bf16x8*)&Bs[cur][(wnr + nt * 16 + li) * 32 + rc];
        __builtin_amdgcn_s_setprio(1);
#pragma unroll
        for (int mt = 0; mt < 4; ++mt)
#pragma unroll
            for (int nt = 0; nt < 4; ++nt)
                acc[mt][nt] = __builtin_amdgcn_mfma_f32_16x16x32_bf16(af[mt], bf_[nt], acc[mt][nt], 0, 0, 0);
        __builtin_amdgcn_s_setprio(0);
        if (kt + 1 < 16) writeA(cur ^ 1, a);   // write-late (T14)
        __syncthreads();
    }
    // epilogue: tsel is block-uniform (512-boundaries are multiples of 128)
    const int colbase = n0 + wnr;
    const int tsel = colbase >> 9;
    const int h = (colbase & 511) >> 6;
    if (tsel < 2) {
        short* __restrict__ dst = (tsel == 0) ? Qo : Ko;
        const float scale = (tsel == 0) ? 0.180336878f : 1.0f;   // 0.125*log2(e)
#pragma unroll
        for (int nt = 0; nt < 4; ++nt) {
            const int d = nt * 16 + li;
            const float bv = bias[colbase + d];
#pragma unroll
            for (int mt = 0; mt < 4; ++mt) {
                const int rowb = m0 + wmr + mt * 16 + lg * 4;
#pragma unroll
                for (int r = 0; r < 4; ++r) {
                    const int row = rowb + r;
                    const int bb = row >> 10, np = row & 1023;
                    const float v = (acc[mt][nt][r] + bv) * scale;
                    dst[((size_t)(bb * 8 + h) * 1024 + np) * 64 + d] = f2bf(v);
                }
            }
        }
    } else {
        // V: wave-private LDS transpose (after final barrier As/Bs are free).
        short* vq = (w == 0) ? As[0] : (w == 1) ? As[1] : (w == 2) ? Bs[0] : Bs[1];
#pragma unroll
        for (int nt = 0; nt < 4; ++nt) {
            const int d = nt * 16 + li;
            const float bv = bias[colbase + d];
#pragma unroll
            for (int mt = 0; mt < 4; ++mt)
#pragma unroll
                for (int r = 0; r < 4; ++r) {
                    const int tk = mt * 16 + lg * 4 + r;
                    vq[d * 64 + (((tk >> 3) ^ (d & 7)) * 8) + (tk & 7)] =
                        f2bf(acc[mt][nt][r] + bv);
                }
        }
        const int bh = (m0 >> 10) * 8 + h;
        const int np0 = (m0 & 1023) + wmr;
#pragma unroll
        for (int pass = 0; pass < 8; ++pass) {
            const int dd = (l >> 3) + pass * 8;
            const int cc = l & 7;
            const bf16x8 vv = *(const bf16x8*)&vq[dd * 64 + ((cc ^ (dd & 7)) * 8)];
            *(bf16x8*)&Vto[((size_t)bh * 64 + dd) * 1024 + np0 + cc * 8] = vv;
        }
    }
}

// ---------- attention: flash over 64-key tiles, K single-buffered ----------
// LDS 32 KB; launch_bounds 4 ((256,5) chokes the allocator to 48 VGPR + spill).
// HW reaches 5 blocks/CU via the LDS limit with full 128-VGPR budget.
__global__ __launch_bounds__(256, 4) void attn_kernel(
    const short* __restrict__ Qg, const short* __restrict__ Kg,
    const short* __restrict__ Vtg, short* __restrict__ Og) {
    __shared__ short Ks[64 * 64];
    __shared__ short Vts[2][64 * 64];
    __shared__ short Ps[4][16 * 64];
    const int t = threadIdx.x, w = t >> 6, l = t & 63, lg = l >> 4, li = l & 15;
    // bijective XCD swizzle: 1024 blocks = 8 XCD x 128 -> 8 bh per XCD
    const int bid = blockIdx.x;
    const int sbid = (bid & 7) * 128 + (bid >> 3);
    const int n0 = (sbid & 15) * 64;
    const int bh = sbid >> 4;
    const int b = bh >> 3, h = bh & 7;

    const int qa = n0 + w * 16 + li;
    const size_t qbase = ((size_t)bh * 1024 + qa) * 64;
    const bf16x8 aq0 = *(const bf16x8*)&Qg[qbase + lg * 8];
    const bf16x8 aq1 = *(const bf16x8*)&Qg[qbase + 32 + lg * 8];

    bf16x8 onesb;
#pragma unroll
    for (int i = 0; i < 8; ++i) onesb[i] = (short)0x3F80;   // bf16 1.0

    f32x4 oacc[4] = {};
    f32x4 oner = {};
    float mrow[4] = {-1e30f, -1e30f, -1e30f, -1e30f};

    const int srow = t >> 3;
    const int sgc = (t & 7) ^ ((t >> 3) & 7);
    const int kc0 = (lg ^ (li & 7)) * 8;
    const int kc1 = kc0 ^ 32;

    auto stageK = [&](int ktile) {
        const int kt = ktile * 64;
        gload_lds16(Kg + ((size_t)bh * 1024 + kt + srow) * 64 + sgc * 8, Ks + t * 8);
        gload_lds16(Kg + ((size_t)bh * 1024 + kt + srow + 32) * 64 + sgc * 8, Ks + (t + 256) * 8);
    };
    auto stageV = [&](int buf, int ktile) {
        const int kt = ktile * 64;
        short* vb = Vts[buf];
        gload_lds16(Vtg + ((size_t)bh * 64 + srow) * 1024 + kt + sgc * 8, vb + t * 8);
        gload_lds16(Vtg + ((size_t)bh * 64 + srow + 32) * 1024 + kt + sgc * 8, vb + (t + 256) * 8);
    };

    stageK(0);
    stageV(0, 0);
    __syncthreads();
    for (int kt = 0; kt < 16; ++kt) {
        const int cur = kt & 1;
        const short* vb = Vts[cur];

        // S = Q K^T from the single K buffer (holds tile kt)
        f32x4 s[4];
        __builtin_amdgcn_s_setprio(1);
#pragma unroll
        for (int nt = 0; nt < 4; ++nt) {
            const int krow = (nt * 16 + li) * 64;
            const bf16x8 bk0 = *(const bf16x8*)&Ks[krow + kc0];
            const bf16x8 bk1 = *(const bf16x8*)&Ks[krow + kc1];
            f32x4 z = {};
            z = __builtin_amdgcn_mfma_f32_16x16x32_bf16(aq0, bk0, z, 0, 0, 0);
            z = __builtin_amdgcn_mfma_f32_16x16x32_bf16(aq1, bk1, z, 0, 0, 0);
            s[nt] = z;
        }
        __builtin_amdgcn_s_setprio(0);
        // all waves done reading K(kt); vmcnt already 0 here -> cheap barrier
        __syncthreads();
        if (kt + 1 < 16) {
            stageK(kt + 1);              // covered by softmax+P+PV below
            stageV(cur ^ 1, kt + 1);
        }

        // online softmax (base-2), defer-max
        float lm[4];
#pragma unroll
        for (int r = 0; r < 4; ++r)
            lm[r] = fmaxf(fmaxf(s[0][r], s[1][r]), fmaxf(s[2][r], s[3][r]));
        const float excess = fmaxf(fmaxf(lm[0] - mrow[0], lm[1] - mrow[1]),
                                   fmaxf(lm[2] - mrow[2], lm[3] - mrow[3]));
        if (__all(excess <= 8.0f)) {
#pragma unroll
            for (int nt = 0; nt < 4; ++nt)
#pragma unroll
                for (int r = 0; r < 4; ++r)
                    s[nt][r] = exp2n(s[nt][r] - mrow[r]);
        } else {
            float mnew[4], sc[4];
#pragma unroll
            for (int r = 0; r < 4; ++r) {
                float v = lm[r];
#pragma unroll
                for (int mm = 8; mm >= 1; mm >>= 1) v = fmaxf(v, __shfl_xor(v, mm));
                mnew[r] = fmaxf(mrow[r], v);
                sc[r] = exp2n(mrow[r] - mnew[r]);
                mrow[r] = mnew[r];
            }
#pragma unroll
            for (int nt = 0; nt < 4; ++nt)
#pragma unroll
                for (int r = 0; r < 4; ++r)
                    s[nt][r] = exp2n(s[nt][r] - mnew[r]);
#pragma unroll
            for (int dt = 0; dt < 4; ++dt)
#pragma unroll
                for (int r = 0; r < 4; ++r) oacc[dt][r] *= sc[r];
#pragma unroll
            for (int r = 0; r < 4; ++r) oner[r] *= sc[r];
        }

        // P -> LDS (swizzled), packed bf16 convert (wave-private)
#pragma unroll
        for (int nt = 0; nt < 4; ++nt)
#pragma unroll
            for (int rp = 0; rp < 2; ++rp) {
                u32 pk;
                asm("v_cvt_pk_bf16_f32 %0, %1, %2"
                    : "=v"(pk) : "v"(s[nt][rp * 2]), "v"(s[nt][rp * 2 + 1]));
                const int prow0 = lg * 4 + rp * 2;
                const int pcbase = nt * 2 + (li >> 3);
                Ps[w][prow0 * 64 + (pcbase ^ (prow0 & 7)) * 8 + (li & 7)] = (short)pk;
                Ps[w][(prow0 + 1) * 64 + (pcbase ^ ((prow0 + 1) & 7)) * 8 + (li & 7)] =
                    (short)(pk >> 16);
            }
        const bf16x8 pa0 = *(const bf16x8*)&Ps[w][li * 64 + kc0];
        const bf16x8 pa1 = *(const bf16x8*)&Ps[w][li * 64 + kc1];
        __builtin_amdgcn_s_setprio(1);
        oner = __builtin_amdgcn_mfma_f32_16x16x32_bf16(pa0, onesb, oner, 0, 0, 0);
        oner = __builtin_amdgcn_mfma_f32_16x16x32_bf16(pa1, onesb, oner, 0, 0, 0);
#pragma unroll
        for (int dt = 0; dt < 4; ++dt) {
            const int vrow = (dt * 16 + li) * 64;
            const bf16x8 bv0 = *(const bf16x8*)&vb[vrow + kc0];
            const bf16x8 bv1 = *(const bf16x8*)&vb[vrow + kc1];
            oacc[dt] = __builtin_amdgcn_mfma_f32_16x16x32_bf16(pa0, bv0, oacc[dt], 0, 0, 0);
            oacc[dt] = __builtin_amdgcn_mfma_f32_16x16x32_bf16(pa1, bv1, oacc[dt], 0, 0, 0);
        }
        __builtin_amdgcn_s_setprio(0);
        // drains this iter's K/V staging; next iter reads them
        __syncthreads();
    }
#pragma unroll
    for (int r = 0; r < 4; ++r) {
        const float inv = 1.f / oner[r];
        const int qq = n0 + w * 16 + lg * 4 + r;
#pragma unroll
        for (int dt = 0; dt < 4; ++dt)
            Og[(size_t)(b * 1024 + qq) * 512 + h * 64 + dt * 16 + li] = f2bf(oacc[dt][r] * inv);
    }
}

// ---------- GEMM2 (8-wave): outT[c][n] = wprojT[c][:] . O[n][:] + b_proj[c] ----------
__global__ __launch_bounds__(512, 2) void gemm_proj(
    const short* __restrict__ At, const short* __restrict__ Bsrc,
    const float* __restrict__ bias, float* __restrict__ out) {
    __shared__ short As[2][128 * 32];
    __shared__ short Bs[2][128 * 32];
    const int t = threadIdx.x, w = t >> 6, l = t & 63;
    const int n0 = blockIdx.x * 128, m0 = blockIdx.y * 128, bz = blockIdx.z;
    const int srow = t >> 2;                        // 0..127
    const int sgc = (t & 3) ^ ((t >> 3) & 3);
    f32x4 acc[4][2] = {};
    const int wmr = (w >> 2) * 64, wnr = (w & 3) * 32;
    const int lg = l >> 4, li = l & 15;
    const int rc = (lg ^ ((li >> 1) & 3)) * 8;

    auto stage = [&](int buf, int k0) {
        gload_lds16(At + (size_t)(m0 + srow) * 512 + k0 + sgc * 8, As[buf] + t * 8);
        gload_lds16(Bsrc + ((size_t)bz * 1024 + n0 + srow) * 512 + k0 + sgc * 8, Bs[buf] + t * 8);
    };

    stage(0, 0);
    __syncthreads();
    for (int kt = 0; kt < 16; ++kt) {
        const int cur = kt & 1;
        if (kt + 1 < 16) stage(cur ^ 1, (kt + 1) * 32);
        bf16x8 af[4], bf_[2];
#pragma unroll
        for (int mt = 0; mt < 4; ++mt)
            af[mt] = *(const bf16x8*)&As[cur][(wmr + mt * 16 + li) * 32 + rc];
#pragma unroll
        for (int nt = 0; nt < 2; ++nt)
            bf_[nt] = *(const bf16x8*)&Bs[cur][(wnr + nt * 16 + li) * 32 + rc];
        __builtin_amdgcn_s_setprio(1);
#pragma unroll
        for (int mt = 0; mt < 4; ++mt)
#pragma unroll
            for (int nt = 0; nt < 2; ++nt)
                acc[mt][nt] = __builtin_amdgcn_mfma_f32_16x16x32_bf16(af[mt], bf_[nt], acc[mt][nt], 0, 0, 0);
        __builtin_amdgcn_s_setprio(0);
        __syncthreads();
    }
#pragma unroll
    for (int mt = 0; mt < 4; ++mt)
#pragma unroll
        for (int r = 0; r < 4; ++r) {
            const int c = m0 + wmr + mt * 16 + lg * 4 + r;
            const float bv = bias[c];
#pragma unroll
            for (int nt = 0; nt < 2; ++nt) {
                const int col = n0 + wnr + nt * 16 + li;
                out[(size_t)(bz * 512 + c) * 1024 + col] = acc[mt][nt][r] + bv;
            }
        }
}

extern "C" void kernel_launch(void* const* d_in, const int* in_sizes, int n_in,
                              void* d_out, int out_size, void* d_ws, size_t ws_size,
                              hipStream_t stream) {
    const float* x      = (const float*)d_in[0];   // (8,512,1024)
    const float* w_qkv  = (const float*)d_in[1];   // (512,1536)
    const float* b_qkv  = (const float*)d_in[2];   // (1536)
    const float* w_proj = (const float*)d_in[3];   // (512,512)
    const float* b_proj = (const float*)d_in[4];   // (512)
    float* out = (float*)d_out;                    // (8,512,1024)

    char* ws = (char*)d_ws;
    size_t off = 0;
    auto carve = [&](size_t bytes) {
        void* p = ws + off;
        off = (off + bytes + 255) & ~(size_t)255;
        return p;
    };
    short* wqkvT  = (short*)carve((size_t)1536 * 512 * 2);
    short* wprojT = (short*)carve((size_t)512 * 512 * 2);
    short* Q      = (short*)carve((size_t)8 * 8 * 1024 * 64 * 2);
    short* K      = (short*)carve((size_t)8 * 8 * 1024 * 64 * 2);
    short* Vt     = (short*)carve((size_t)8 * 8 * 64 * 1024 * 2);
    short* O      = (short*)carve((size_t)8 * 1024 * 512 * 2);

    dim3 tb(32, 8);
    transpose_cvt<<<dim3(1536 / 32, 512 / 32, 1), tb, 0, stream>>>(w_qkv, wqkvT, 512, 1536);
    transpose_cvt<<<dim3(512 / 32, 512 / 32, 1), tb, 0, stream>>>(w_proj, wprojT, 512, 512);
    gemm_qkv<<<dim3(768), 256, 0, stream>>>(x, wqkvT, b_qkv, Q, K, Vt);
    attn_kernel<<<dim3(1024), 256, 0, stream>>>(Q, K, Vt, O);
    gemm_proj<<<dim3(8, 4, 8), 512, 0, stream>>>(wprojT, O, b_proj, out);
}